// Round 5
// baseline (931.024 us; speedup 1.0000x reference)
//
#include <hip/hip_runtime.h>
#include <cstddef>

#define B_ 64
#define T_ 256
#define C_ 2048
#define H_ 512
#define O_ 11
#define THRESH 1.0f
#define LEAK_ 0.003f
#define OLEAK_ 0.0015f

typedef float v2f __attribute__((ext_vector_type(2)));

__device__ __forceinline__ float4 f4add(float4 a, float4 b) {
    return make_float4(a.x + b.x, a.y + b.y, a.z + b.z, a.w + b.w);
}

// ---------------------------------------------------------------------------
// Kernel 1: transpose w_rec (H x H) -> w_recT (coalesced recurrent gather).
// ---------------------------------------------------------------------------
__global__ __launch_bounds__(256) void transpose_wrec(const float* __restrict__ w,
                                                      float* __restrict__ wt) {
    __shared__ float tile[32][33];
    int tx = threadIdx.x, ty = threadIdx.y;           // block (32, 8)
    int x = blockIdx.x * 32 + tx;
    int y = blockIdx.y * 32 + ty;
#pragma unroll
    for (int i = 0; i < 32; i += 8)
        tile[ty + i][tx] = w[(size_t)(y + i) * H_ + x];
    __syncthreads();
    int x2 = blockIdx.y * 32 + tx;
    int y2 = blockIdx.x * 32 + ty;
#pragma unroll
    for (int i = 0; i < 32; i += 8)
        wt[(size_t)(y2 + i) * H_ + x2] = tile[tx][ty + i];
}

// ---------------------------------------------------------------------------
// Kernel 2: split-K GEMM  P[s] = X @ w1^T.  (R2's proven 256-thread shape +
// LDS pad(+4) + register prefetch of tile k+1 + XCD swizzle so the 4 bx
// blocks sharing an x-tile run on ONE XCD -> x fetched once per XCD.)
// ---------------------------------------------------------------------------
#define BM 128
#define BN 128
#define BK 16

template <int S>
__global__ __launch_bounds__(256) void gemm_ff(const float* __restrict__ A,
                                               const float* __restrict__ Bw,
                                               float* __restrict__ Pout) {
    const int K = C_;
    const int N = H_;
    const int kLen = C_ / S;

    // swizzled decode: lid%8 = XCD slot j; each XCD gets all 4 bx of one by.
    int lid = blockIdx.x;
    int z   = lid >> 9;              // 512 blocks per k-chunk (4 bx * 128 by)
    int rem = lid & 511;
    int by  = (rem >> 5) * 8 + (rem & 7);
    int bx  = (rem >> 3) & 3;
    const int kBase = z * kLen;

    __shared__ float As[BK][BM + 4];
    __shared__ float Bs[BK][BN + 4];

    const int t  = threadIdx.x;
    const int tx = t & 15;        // n-dir
    const int ty = t >> 4;        // m-dir
    const int lr = t >> 2;        // load row 0..63
    const int lc = (t & 3) * 4;   // load col 0,4,8,12

    const float* Ap = A  + (size_t)(by * BM + lr) * K + kBase + lc;
    const float* Bp = Bw + (size_t)(bx * BN + lr) * K + kBase + lc;

    float4 pa0 = *(const float4*)(Ap);
    float4 pa1 = *(const float4*)(Ap + (size_t)64 * K);
    float4 pb0 = *(const float4*)(Bp);
    float4 pb1 = *(const float4*)(Bp + (size_t)64 * K);
    Ap += BK; Bp += BK;

    v2f acc[8][4];
#pragma unroll
    for (int i = 0; i < 8; ++i)
#pragma unroll
        for (int j = 0; j < 4; ++j) acc[i][j] = (v2f){0.f, 0.f};

    const int nT = kLen / BK;
    for (int kt = 0; kt < nT; ++kt) {
        __syncthreads();
        As[lc + 0][lr] = pa0.x; As[lc + 1][lr] = pa0.y;
        As[lc + 2][lr] = pa0.z; As[lc + 3][lr] = pa0.w;
        As[lc + 0][lr + 64] = pa1.x; As[lc + 1][lr + 64] = pa1.y;
        As[lc + 2][lr + 64] = pa1.z; As[lc + 3][lr + 64] = pa1.w;
        Bs[lc + 0][lr] = pb0.x; Bs[lc + 1][lr] = pb0.y;
        Bs[lc + 2][lr] = pb0.z; Bs[lc + 3][lr] = pb0.w;
        Bs[lc + 0][lr + 64] = pb1.x; Bs[lc + 1][lr + 64] = pb1.y;
        Bs[lc + 2][lr + 64] = pb1.z; Bs[lc + 3][lr + 64] = pb1.w;
        __syncthreads();

        if (kt + 1 < nT) {    // prefetch next tile; latency hides under FMAs
            pa0 = *(const float4*)(Ap);
            pa1 = *(const float4*)(Ap + (size_t)64 * K);
            pb0 = *(const float4*)(Bp);
            pb1 = *(const float4*)(Bp + (size_t)64 * K);
            Ap += BK; Bp += BK;
        }

#pragma unroll
        for (int k = 0; k < BK; ++k) {
            float4 alo = *(const float4*)&As[k][ty * 4];
            float4 ahi = *(const float4*)&As[k][64 + ty * 4];
            float4 blo = *(const float4*)&Bs[k][tx * 4];
            float4 bhi = *(const float4*)&Bs[k][64 + tx * 4];
            v2f b0v = {blo.x, blo.y}, b1v = {blo.z, blo.w};
            v2f b2v = {bhi.x, bhi.y}, b3v = {bhi.z, bhi.w};
            float av[8] = {alo.x, alo.y, alo.z, alo.w, ahi.x, ahi.y, ahi.z, ahi.w};
#pragma unroll
            for (int i = 0; i < 8; ++i) {
                v2f ai = {av[i], av[i]};
                acc[i][0] += ai * b0v;
                acc[i][1] += ai * b1v;
                acc[i][2] += ai * b2v;
                acc[i][3] += ai * b3v;
            }
        }
    }

    float* P = Pout + (size_t)z * ((size_t)B_ * T_ * H_);
#pragma unroll
    for (int i = 0; i < 8; ++i) {
        int row = by * BM + (i < 4 ? ty * 4 + i : 64 + ty * 4 + (i - 4));
        float* Cp = P + (size_t)row * N + bx * BN;
        float4 c0 = {acc[i][0].x, acc[i][0].y, acc[i][1].x, acc[i][1].y};
        float4 c1 = {acc[i][2].x, acc[i][2].y, acc[i][3].x, acc[i][3].y};
        *(float4*)(Cp + tx * 4)      = c0;
        *(float4*)(Cp + 64 + tx * 4) = c1;
    }
}

// ---------------------------------------------------------------------------
// Kernel 3: recurrent LIF scan. One wave per batch element; lane L owns
// neurons 8L..8L+7 (PACKED) so every memory op is float4:
//   - I1 row read  = 2 dwordx4/lane (coalesced), split-K partials summed here
//   - gather/spike = 2 dwordx4/lane
// Depth-2 ping-pong I1 prefetch: row t+2 issued at end of step t -> ~2 steps
// old at consumption (>= HBM latency); per-step gather wait only drains a
// nearly-complete 1-step-old buffer (vmcnt completes in order).
// No arrays with dynamic indices (no scratch). Output work deferred to a
// post-loop phase via ballot masks in LDS.
// ---------------------------------------------------------------------------
template <int S>
__global__ __launch_bounds__(64) void snn_rec(const float* __restrict__ P,
                                              const float* __restrict__ wrT,
                                              const float* __restrict__ w2,
                                              float* __restrict__ out) {
    const int b = blockIdx.x;
    const int L = threadIdx.x;
    const size_t PARTF = (size_t)B_ * T_ * H_;

    __shared__ int   smask_lo[T_ * 8];   // 8 KB
    __shared__ int   smask_hi[T_ * 8];   // 8 KB
    __shared__ int   slist[H_];          // 2 KB  (single buffer: read-then-write per step)
    __shared__ float w2t[H_ * 12];       // 24 KB
    __shared__ float i2s[T_ * 12];       // 12 KB

    const float* rowb = P + (size_t)b * T_ * H_ + 8 * L;
    const float* wrL  = wrT + 8 * L;

    float v1[8];
#pragma unroll
    for (int r = 0; r < 8; ++r) v1[r] = 0.f;
    int pcnt = 0;

    const unsigned long long below = (L == 0) ? 0ull : ((~0ull) >> (64 - L));

    // ping-pong prefetch buffers: pA = even rows, pB = odd rows
    float4 pA[S][2], pB[S][2];
#pragma unroll
    for (int s = 0; s < S; ++s) {
        pA[s][0] = *(const float4*)(rowb + s * PARTF);
        pA[s][1] = *(const float4*)(rowb + s * PARTF + 4);
        pB[s][0] = *(const float4*)(rowb + s * PARTF + H_);
        pB[s][1] = *(const float4*)(rowb + s * PARTF + H_ + 4);
    }

#define SNN_STEP(tcur, PC)                                                     \
    {                                                                          \
        const int t = (tcur);                                                  \
        float4 rc0 = make_float4(-LEAK_, -LEAK_, -LEAK_, -LEAK_);              \
        float4 rc1 = rc0;                                                      \
        _Pragma("unroll")                                                      \
        for (int s = 0; s < S; ++s) {                                          \
            rc0 = f4add(rc0, PC[s][0]);                                        \
            rc1 = f4add(rc1, PC[s][1]);                                        \
        }                                                                      \
        if (pcnt > 0) {                                                        \
            const int lim = pcnt - 1;                                          \
            for (int base = 0; base < pcnt; base += 8) {                       \
                int i1q = base + 1 > lim ? lim : base + 1;                     \
                int i2q = base + 2 > lim ? lim : base + 2;                     \
                int i3q = base + 3 > lim ? lim : base + 3;                     \
                int i4q = base + 4 > lim ? lim : base + 4;                     \
                int i5q = base + 5 > lim ? lim : base + 5;                     \
                int i6q = base + 6 > lim ? lim : base + 6;                     \
                int i7q = base + 7 > lim ? lim : base + 7;                     \
                int j0 = slist[base];                                          \
                int j1 = slist[i1q]; int j2 = slist[i2q];                      \
                int j3 = slist[i3q]; int j4 = slist[i4q];                      \
                int j5 = slist[i5q]; int j6 = slist[i6q];                      \
                int j7 = slist[i7q];                                           \
                const float* q0 = wrL + (size_t)j0 * H_;                       \
                const float* q1 = wrL + (size_t)j1 * H_;                       \
                const float* q2 = wrL + (size_t)j2 * H_;                       \
                const float* q3 = wrL + (size_t)j3 * H_;                       \
                const float* q4 = wrL + (size_t)j4 * H_;                       \
                const float* q5 = wrL + (size_t)j5 * H_;                       \
                const float* q6 = wrL + (size_t)j6 * H_;                       \
                const float* q7 = wrL + (size_t)j7 * H_;                       \
                float4 g0a = *(const float4*)q0, g0b = *(const float4*)(q0 + 4); \
                float4 g1a = *(const float4*)q1, g1b = *(const float4*)(q1 + 4); \
                float4 g2a = *(const float4*)q2, g2b = *(const float4*)(q2 + 4); \
                float4 g3a = *(const float4*)q3, g3b = *(const float4*)(q3 + 4); \
                float4 g4a = *(const float4*)q4, g4b = *(const float4*)(q4 + 4); \
                float4 g5a = *(const float4*)q5, g5b = *(const float4*)(q5 + 4); \
                float4 g6a = *(const float4*)q6, g6b = *(const float4*)(q6 + 4); \
                float4 g7a = *(const float4*)q7, g7b = *(const float4*)(q7 + 4); \
                rc0 = f4add(rc0, g0a); rc1 = f4add(rc1, g0b);                  \
                if (base + 1 < pcnt) { rc0 = f4add(rc0, g1a); rc1 = f4add(rc1, g1b); } \
                if (base + 2 < pcnt) { rc0 = f4add(rc0, g2a); rc1 = f4add(rc1, g2b); } \
                if (base + 3 < pcnt) { rc0 = f4add(rc0, g3a); rc1 = f4add(rc1, g3b); } \
                if (base + 4 < pcnt) { rc0 = f4add(rc0, g4a); rc1 = f4add(rc1, g4b); } \
                if (base + 5 < pcnt) { rc0 = f4add(rc0, g5a); rc1 = f4add(rc1, g5b); } \
                if (base + 6 < pcnt) { rc0 = f4add(rc0, g6a); rc1 = f4add(rc1, g6b); } \
                if (base + 7 < pcnt) { rc0 = f4add(rc0, g7a); rc1 = f4add(rc1, g7b); } \
            }                                                                  \
        }                                                                      \
        float rcv[8] = {rc0.x, rc0.y, rc0.z, rc0.w, rc1.x, rc1.y, rc1.z, rc1.w}; \
        unsigned long long mk0, mk1, mk2, mk3, mk4, mk5, mk6, mk7;             \
        {                                                                      \
            v1[0] += rcv[0]; bool sp = v1[0] >= THRESH; mk0 = __ballot(sp); if (sp) v1[0] -= THRESH; \
        }                                                                      \
        { v1[1] += rcv[1]; bool sp = v1[1] >= THRESH; mk1 = __ballot(sp); if (sp) v1[1] -= THRESH; } \
        { v1[2] += rcv[2]; bool sp = v1[2] >= THRESH; mk2 = __ballot(sp); if (sp) v1[2] -= THRESH; } \
        { v1[3] += rcv[3]; bool sp = v1[3] >= THRESH; mk3 = __ballot(sp); if (sp) v1[3] -= THRESH; } \
        { v1[4] += rcv[4]; bool sp = v1[4] >= THRESH; mk4 = __ballot(sp); if (sp) v1[4] -= THRESH; } \
        { v1[5] += rcv[5]; bool sp = v1[5] >= THRESH; mk5 = __ballot(sp); if (sp) v1[5] -= THRESH; } \
        { v1[6] += rcv[6]; bool sp = v1[6] >= THRESH; mk6 = __ballot(sp); if (sp) v1[6] -= THRESH; } \
        { v1[7] += rcv[7]; bool sp = v1[7] >= THRESH; mk7 = __ballot(sp); if (sp) v1[7] -= THRESH; } \
        if (L == 0) {                                                          \
            smask_lo[t * 8 + 0] = (int)(mk0 & 0xffffffffull); smask_hi[t * 8 + 0] = (int)(mk0 >> 32); \
            smask_lo[t * 8 + 1] = (int)(mk1 & 0xffffffffull); smask_hi[t * 8 + 1] = (int)(mk1 >> 32); \
            smask_lo[t * 8 + 2] = (int)(mk2 & 0xffffffffull); smask_hi[t * 8 + 2] = (int)(mk2 >> 32); \
            smask_lo[t * 8 + 3] = (int)(mk3 & 0xffffffffull); smask_hi[t * 8 + 3] = (int)(mk3 >> 32); \
            smask_lo[t * 8 + 4] = (int)(mk4 & 0xffffffffull); smask_hi[t * 8 + 4] = (int)(mk4 >> 32); \
            smask_lo[t * 8 + 5] = (int)(mk5 & 0xffffffffull); smask_hi[t * 8 + 5] = (int)(mk5 >> 32); \
            smask_lo[t * 8 + 6] = (int)(mk6 & 0xffffffffull); smask_hi[t * 8 + 6] = (int)(mk6 >> 32); \
            smask_lo[t * 8 + 7] = (int)(mk7 & 0xffffffffull); smask_hi[t * 8 + 7] = (int)(mk7 >> 32); \
        }                                                                      \
        int Sl = (int)__popcll(mk0 & below) + (int)__popcll(mk1 & below) +     \
                 (int)__popcll(mk2 & below) + (int)__popcll(mk3 & below) +     \
                 (int)__popcll(mk4 & below) + (int)__popcll(mk5 & below) +     \
                 (int)__popcll(mk6 & below) + (int)__popcll(mk7 & below);      \
        int run = 0;                                                           \
        if ((mk0 >> L) & 1ull) { slist[Sl + run] = 8 * L + 0; ++run; }         \
        if ((mk1 >> L) & 1ull) { slist[Sl + run] = 8 * L + 1; ++run; }         \
        if ((mk2 >> L) & 1ull) { slist[Sl + run] = 8 * L + 2; ++run; }         \
        if ((mk3 >> L) & 1ull) { slist[Sl + run] = 8 * L + 3; ++run; }         \
        if ((mk4 >> L) & 1ull) { slist[Sl + run] = 8 * L + 4; ++run; }         \
        if ((mk5 >> L) & 1ull) { slist[Sl + run] = 8 * L + 5; ++run; }         \
        if ((mk6 >> L) & 1ull) { slist[Sl + run] = 8 * L + 6; ++run; }         \
        if ((mk7 >> L) & 1ull) { slist[Sl + run] = 8 * L + 7; ++run; }         \
        pcnt = (int)__popcll(mk0) + (int)__popcll(mk1) + (int)__popcll(mk2) +  \
               (int)__popcll(mk3) + (int)__popcll(mk4) + (int)__popcll(mk5) +  \
               (int)__popcll(mk6) + (int)__popcll(mk7);                        \
        /* refill this buffer with row t+2 (depth-2 pipeline) */               \
        {                                                                      \
            int nr = t + 2 < T_ ? t + 2 : T_ - 1;                              \
            const float* nb2 = rowb + (size_t)nr * H_;                         \
            _Pragma("unroll")                                                  \
            for (int s = 0; s < S; ++s) {                                      \
                PC[s][0] = *(const float4*)(nb2 + s * PARTF);                  \
                PC[s][1] = *(const float4*)(nb2 + s * PARTF + 4);              \
            }                                                                  \
        }                                                                      \
    }

    for (int tt = 0; tt < T_; tt += 2) {
        SNN_STEP(tt, pA)
        SNN_STEP(tt + 1, pB)
    }
#undef SNN_STEP

    __syncthreads();

    // ---- phase 2: output neurons, off the recurrence ----
    for (int j = L; j < H_; j += 64) {
#pragma unroll
        for (int o = 0; o < O_; ++o) w2t[j * 12 + o] = w2[o * H_ + j];
    }
    __syncthreads();

    for (int tt = L; tt < T_; tt += 64) {
        float s0 = 0.f, s1 = 0.f, s2 = 0.f, s3 = 0.f, s4 = 0.f, s5 = 0.f,
              s6 = 0.f, s7 = 0.f, s8 = 0.f, s9 = 0.f, s10 = 0.f;
#pragma unroll
        for (int r = 0; r < 8; ++r) {
            unsigned long long m =
                ((unsigned long long)(unsigned)smask_lo[tt * 8 + r]) |
                (((unsigned long long)(unsigned)smask_hi[tt * 8 + r]) << 32);
            while (m) {
                int l = __builtin_ctzll(m);
                m &= m - 1;
                const float* wp = &w2t[(8 * l + r) * 12];
                s0 += wp[0]; s1 += wp[1]; s2 += wp[2]; s3 += wp[3];
                s4 += wp[4]; s5 += wp[5]; s6 += wp[6]; s7 += wp[7];
                s8 += wp[8]; s9 += wp[9]; s10 += wp[10];
            }
        }
        float* ip = &i2s[tt * 12];
        ip[0] = s0; ip[1] = s1; ip[2] = s2; ip[3] = s3; ip[4] = s4;
        ip[5] = s5; ip[6] = s6; ip[7] = s7; ip[8] = s8; ip[9] = s9; ip[10] = s10;
    }
    __syncthreads();

    if (L < O_) {
        float v2 = 0.f, osum = 0.f;
        for (int t = 0; t < T_; ++t) {
            v2 = v2 + i2s[t * 12 + L] - OLEAK_;
            v2 = v2 > 0.f ? v2 : 0.f;
            osum += v2;
        }
        out[b * O_ + L] = osum * (1.0f / (float)T_);
    }
}

// ---------------------------------------------------------------------------
extern "C" void kernel_launch(void* const* d_in, const int* in_sizes, int n_in,
                              void* d_out, int out_size, void* d_ws, size_t ws_size,
                              hipStream_t stream) {
    const float* x     = (const float*)d_in[0];   // (B,T,C)
    const float* w1    = (const float*)d_in[1];   // (H,C)
    const float* w_rec = (const float*)d_in[2];   // (H,H)
    const float* w2    = (const float*)d_in[3];   // (O,H)
    float* out = (float*)d_out;                   // (B,O)

    const size_t PART = (size_t)B_ * T_ * H_ * sizeof(float);   // 32 MB
    const size_t WRT  = (size_t)H_ * H_ * sizeof(float);        // 1 MB

    int S = 1;
    if (ws_size >= 4 * PART + WRT) S = 4;
    else if (ws_size >= 2 * PART + WRT) S = 2;

    float* P   = (float*)d_ws;
    float* wrT = (float*)((char*)d_ws + (size_t)S * PART);

    transpose_wrec<<<dim3(H_ / 32, H_ / 32), dim3(32, 8), 0, stream>>>(w_rec, wrT);

    switch (S) {
        case 4:
            gemm_ff<4><<<dim3(512 * 4), dim3(256), 0, stream>>>(x, w1, P);
            snn_rec<4><<<dim3(B_), dim3(64), 0, stream>>>(P, wrT, w2, out);
            break;
        case 2:
            gemm_ff<2><<<dim3(512 * 2), dim3(256), 0, stream>>>(x, w1, P);
            snn_rec<2><<<dim3(B_), dim3(64), 0, stream>>>(P, wrT, w2, out);
            break;
        default:
            gemm_ff<1><<<dim3(512), dim3(256), 0, stream>>>(x, w1, P);
            snn_rec<1><<<dim3(B_), dim3(64), 0, stream>>>(P, wrT, w2, out);
            break;
    }
}

// Round 6
// 780.828 us; speedup vs baseline: 1.1924x; 1.1924x over previous
//
#include <hip/hip_runtime.h>
#include <cstddef>

#define B_ 64
#define T_ 256
#define C_ 2048
#define H_ 512
#define O_ 11
#define THRESH 1.0f
#define LEAK_ 0.003f
#define OLEAK_ 0.0015f

typedef float v2f __attribute__((ext_vector_type(2)));

__device__ __forceinline__ float4 f4add(float4 a, float4 b) {
    return make_float4(a.x + b.x, a.y + b.y, a.z + b.z, a.w + b.w);
}

// ---------------------------------------------------------------------------
// Kernel 1: transpose w_rec (H x H) -> w_recT (coalesced recurrent gather).
// ---------------------------------------------------------------------------
__global__ __launch_bounds__(256) void transpose_wrec(const float* __restrict__ w,
                                                      float* __restrict__ wt) {
    __shared__ float tile[32][33];
    int tx = threadIdx.x, ty = threadIdx.y;           // block (32, 8)
    int x = blockIdx.x * 32 + tx;
    int y = blockIdx.y * 32 + ty;
#pragma unroll
    for (int i = 0; i < 32; i += 8)
        tile[ty + i][tx] = w[(size_t)(y + i) * H_ + x];
    __syncthreads();
    int x2 = blockIdx.y * 32 + tx;
    int y2 = blockIdx.x * 32 + ty;
#pragma unroll
    for (int i = 0; i < 32; i += 8)
        wt[(size_t)(y2 + i) * H_ + x2] = tile[tx][ty + i];
}

// ---------------------------------------------------------------------------
// Kernel 2: split-K GEMM  P[s] = X @ w1^T.  R2's proven 256-thread shape
// (grid 4 x 128 x S) + LDS pad(+4) + register prefetch of tile k+1.
// ---------------------------------------------------------------------------
#define BM 128
#define BN 128
#define BK 16

template <int S>
__global__ __launch_bounds__(256) void gemm_ff(const float* __restrict__ A,
                                               const float* __restrict__ Bw,
                                               float* __restrict__ Pout) {
    const int K = C_;
    const int N = H_;
    const int kLen  = C_ / S;
    const int kBase = blockIdx.z * kLen;

    __shared__ float As[BK][BM + 4];
    __shared__ float Bs[BK][BN + 4];

    const int t  = threadIdx.x;
    const int tx = t & 15;        // n-dir
    const int ty = t >> 4;        // m-dir
    const int lr = t >> 2;        // load row 0..63
    const int lc = (t & 3) * 4;   // load col 0,4,8,12

    const float* Ap = A  + (size_t)(blockIdx.y * BM + lr) * K + kBase + lc;
    const float* Bp = Bw + (size_t)(blockIdx.x * BN + lr) * K + kBase + lc;

    float4 pa0 = *(const float4*)(Ap);
    float4 pa1 = *(const float4*)(Ap + (size_t)64 * K);
    float4 pb0 = *(const float4*)(Bp);
    float4 pb1 = *(const float4*)(Bp + (size_t)64 * K);
    Ap += BK; Bp += BK;

    v2f acc[8][4];
#pragma unroll
    for (int i = 0; i < 8; ++i)
#pragma unroll
        for (int j = 0; j < 4; ++j) acc[i][j] = (v2f){0.f, 0.f};

    const int nT = kLen / BK;
    for (int kt = 0; kt < nT; ++kt) {
        __syncthreads();
        As[lc + 0][lr] = pa0.x; As[lc + 1][lr] = pa0.y;
        As[lc + 2][lr] = pa0.z; As[lc + 3][lr] = pa0.w;
        As[lc + 0][lr + 64] = pa1.x; As[lc + 1][lr + 64] = pa1.y;
        As[lc + 2][lr + 64] = pa1.z; As[lc + 3][lr + 64] = pa1.w;
        Bs[lc + 0][lr] = pb0.x; Bs[lc + 1][lr] = pb0.y;
        Bs[lc + 2][lr] = pb0.z; Bs[lc + 3][lr] = pb0.w;
        Bs[lc + 0][lr + 64] = pb1.x; Bs[lc + 1][lr + 64] = pb1.y;
        Bs[lc + 2][lr + 64] = pb1.z; Bs[lc + 3][lr + 64] = pb1.w;
        __syncthreads();

        if (kt + 1 < nT) {    // prefetch next tile; latency hides under FMAs
            pa0 = *(const float4*)(Ap);
            pa1 = *(const float4*)(Ap + (size_t)64 * K);
            pb0 = *(const float4*)(Bp);
            pb1 = *(const float4*)(Bp + (size_t)64 * K);
            Ap += BK; Bp += BK;
        }

#pragma unroll
        for (int k = 0; k < BK; ++k) {
            float4 alo = *(const float4*)&As[k][ty * 4];
            float4 ahi = *(const float4*)&As[k][64 + ty * 4];
            float4 blo = *(const float4*)&Bs[k][tx * 4];
            float4 bhi = *(const float4*)&Bs[k][64 + tx * 4];
            v2f b0v = {blo.x, blo.y}, b1v = {blo.z, blo.w};
            v2f b2v = {bhi.x, bhi.y}, b3v = {bhi.z, bhi.w};
            float av[8] = {alo.x, alo.y, alo.z, alo.w, ahi.x, ahi.y, ahi.z, ahi.w};
#pragma unroll
            for (int i = 0; i < 8; ++i) {
                v2f ai = {av[i], av[i]};
                acc[i][0] += ai * b0v;
                acc[i][1] += ai * b1v;
                acc[i][2] += ai * b2v;
                acc[i][3] += ai * b3v;
            }
        }
    }

    float* P = Pout + (size_t)blockIdx.z * ((size_t)B_ * T_ * H_);
#pragma unroll
    for (int i = 0; i < 8; ++i) {
        int row = blockIdx.y * BM + (i < 4 ? ty * 4 + i : 64 + ty * 4 + (i - 4));
        float* Cp = P + (size_t)row * N + blockIdx.x * BN;
        float4 c0 = {acc[i][0].x, acc[i][0].y, acc[i][1].x, acc[i][1].y};
        float4 c1 = {acc[i][2].x, acc[i][2].y, acc[i][3].x, acc[i][3].y};
        *(float4*)(Cp + tx * 4)      = c0;
        *(float4*)(Cp + 64 + tx * 4) = c1;
    }
}

// ---------------------------------------------------------------------------
// Kernel 3: recurrent LIF scan. One block (192 threads = 3 waves) per batch:
//   wave 0 (L=0..63): the recurrence, lane L owns neurons 8L..8L+7.
//     Feedforward current comes from the LDS ring (lgkmcnt), so wave 0's
//     vmem queue holds ONLY the L2-hot wrT gather loads -> no HBM latency
//     on the serial chain (the R3/R4/R5 failure mode).
//   waves 1-2: producers streaming P rows (split-K partials pre-summed)
//     into a 2x16-row LDS ring, one half-window ahead of the consumer.
// One __syncthreads per 16 steps. Output neurons deferred to phase 2.
// ---------------------------------------------------------------------------
template <int S>
__global__ __launch_bounds__(192) void snn_rec(const float* __restrict__ P,
                                               const float* __restrict__ wrT,
                                               const float* __restrict__ w2,
                                               float* __restrict__ out) {
    const int b   = blockIdx.x;
    const int tid = threadIdx.x;
    const int L   = tid & 63;
    const int wid = tid >> 6;          // 0 = consumer, 1..2 = producers
    const size_t PARTF = (size_t)B_ * T_ * H_;

    __shared__ float i1buf[32 * H_];     // 64 KB ring: 2 halves x 16 rows
    __shared__ int   smask_lo[T_ * 8];   // 8 KB
    __shared__ int   smask_hi[T_ * 8];   // 8 KB
    __shared__ int   slist[H_];          // 2 KB (read-then-write per step)
    __shared__ float w2t[H_ * 12];       // 24 KB
    __shared__ float i2s[T_ * 12];       // 12 KB

    const float* wrL = wrT + 8 * L;

    float v1[8];
#pragma unroll
    for (int r = 0; r < 8; ++r) v1[r] = 0.f;
    int pcnt = 0;
    const unsigned long long below = (L == 0) ? 0ull : ((~0ull) >> (64 - L));

    // ---- producer: fill half-window w (16 rows) of the ring ----
#define FILL_HALF(w)                                                           \
    {                                                                          \
        const int rbase = (wid - 1) * 8;       /* 8 rows per producer */       \
        _Pragma("unroll")                                                      \
        for (int rr = 0; rr < 8; rr += 4) {                                    \
            float4 acc0[4], acc1[4];                                           \
            _Pragma("unroll")                                                  \
            for (int q = 0; q < 4; ++q) {                                      \
                const int step = (w) * 16 + rbase + rr + q;                    \
                const float* src = P + ((size_t)b * T_ + step) * H_ + 8 * L;   \
                float4 s0 = *(const float4*)(src);                             \
                float4 s1 = *(const float4*)(src + 4);                         \
                _Pragma("unroll")                                              \
                for (int s = 1; s < S; ++s) {                                  \
                    s0 = f4add(s0, *(const float4*)(src + (size_t)s * PARTF)); \
                    s1 = f4add(s1, *(const float4*)(src + (size_t)s * PARTF + 4)); \
                }                                                              \
                acc0[q] = s0; acc1[q] = s1;                                    \
            }                                                                  \
            _Pragma("unroll")                                                  \
            for (int q = 0; q < 4; ++q) {                                      \
                const int slot = ((w) & 1) * 16 + rbase + rr + q;              \
                *(float4*)&i1buf[slot * H_ + 8 * L]     = acc0[q];             \
                *(float4*)&i1buf[slot * H_ + 8 * L + 4] = acc1[q];             \
            }                                                                  \
        }                                                                      \
    }

    // ---- consumer: one LIF step; ff current from LDS ring slot ----
#define SNN_STEP(tcur, slotidx)                                                \
    {                                                                          \
        const int t = (tcur);                                                  \
        float4 f0 = *(const float4*)&i1buf[(slotidx) * H_ + 8 * L];            \
        float4 f1 = *(const float4*)&i1buf[(slotidx) * H_ + 8 * L + 4];        \
        float4 rc0 = make_float4(-LEAK_, -LEAK_, -LEAK_, -LEAK_);              \
        float4 rc1 = rc0;                                                      \
        rc0 = f4add(rc0, f0); rc1 = f4add(rc1, f1);                            \
        if (pcnt > 0) {                                                        \
            const int lim = pcnt - 1;                                          \
            for (int base = 0; base < pcnt; base += 8) {                       \
                int i1q = base + 1 > lim ? lim : base + 1;                     \
                int i2q = base + 2 > lim ? lim : base + 2;                     \
                int i3q = base + 3 > lim ? lim : base + 3;                     \
                int i4q = base + 4 > lim ? lim : base + 4;                     \
                int i5q = base + 5 > lim ? lim : base + 5;                     \
                int i6q = base + 6 > lim ? lim : base + 6;                     \
                int i7q = base + 7 > lim ? lim : base + 7;                     \
                int j0 = slist[base];                                          \
                int j1 = slist[i1q]; int j2 = slist[i2q];                      \
                int j3 = slist[i3q]; int j4 = slist[i4q];                      \
                int j5 = slist[i5q]; int j6 = slist[i6q];                      \
                int j7 = slist[i7q];                                           \
                const float* q0 = wrL + (size_t)j0 * H_;                       \
                const float* q1 = wrL + (size_t)j1 * H_;                       \
                const float* q2 = wrL + (size_t)j2 * H_;                       \
                const float* q3 = wrL + (size_t)j3 * H_;                       \
                const float* q4 = wrL + (size_t)j4 * H_;                       \
                const float* q5 = wrL + (size_t)j5 * H_;                       \
                const float* q6 = wrL + (size_t)j6 * H_;                       \
                const float* q7 = wrL + (size_t)j7 * H_;                       \
                float4 g0a = *(const float4*)q0, g0b = *(const float4*)(q0 + 4); \
                float4 g1a = *(const float4*)q1, g1b = *(const float4*)(q1 + 4); \
                float4 g2a = *(const float4*)q2, g2b = *(const float4*)(q2 + 4); \
                float4 g3a = *(const float4*)q3, g3b = *(const float4*)(q3 + 4); \
                float4 g4a = *(const float4*)q4, g4b = *(const float4*)(q4 + 4); \
                float4 g5a = *(const float4*)q5, g5b = *(const float4*)(q5 + 4); \
                float4 g6a = *(const float4*)q6, g6b = *(const float4*)(q6 + 4); \
                float4 g7a = *(const float4*)q7, g7b = *(const float4*)(q7 + 4); \
                rc0 = f4add(rc0, g0a); rc1 = f4add(rc1, g0b);                  \
                if (base + 1 < pcnt) { rc0 = f4add(rc0, g1a); rc1 = f4add(rc1, g1b); } \
                if (base + 2 < pcnt) { rc0 = f4add(rc0, g2a); rc1 = f4add(rc1, g2b); } \
                if (base + 3 < pcnt) { rc0 = f4add(rc0, g3a); rc1 = f4add(rc1, g3b); } \
                if (base + 4 < pcnt) { rc0 = f4add(rc0, g4a); rc1 = f4add(rc1, g4b); } \
                if (base + 5 < pcnt) { rc0 = f4add(rc0, g5a); rc1 = f4add(rc1, g5b); } \
                if (base + 6 < pcnt) { rc0 = f4add(rc0, g6a); rc1 = f4add(rc1, g6b); } \
                if (base + 7 < pcnt) { rc0 = f4add(rc0, g7a); rc1 = f4add(rc1, g7b); } \
            }                                                                  \
        }                                                                      \
        float rcv[8] = {rc0.x, rc0.y, rc0.z, rc0.w, rc1.x, rc1.y, rc1.z, rc1.w}; \
        unsigned long long mk0, mk1, mk2, mk3, mk4, mk5, mk6, mk7;             \
        { v1[0] += rcv[0]; bool sp = v1[0] >= THRESH; mk0 = __ballot(sp); if (sp) v1[0] -= THRESH; } \
        { v1[1] += rcv[1]; bool sp = v1[1] >= THRESH; mk1 = __ballot(sp); if (sp) v1[1] -= THRESH; } \
        { v1[2] += rcv[2]; bool sp = v1[2] >= THRESH; mk2 = __ballot(sp); if (sp) v1[2] -= THRESH; } \
        { v1[3] += rcv[3]; bool sp = v1[3] >= THRESH; mk3 = __ballot(sp); if (sp) v1[3] -= THRESH; } \
        { v1[4] += rcv[4]; bool sp = v1[4] >= THRESH; mk4 = __ballot(sp); if (sp) v1[4] -= THRESH; } \
        { v1[5] += rcv[5]; bool sp = v1[5] >= THRESH; mk5 = __ballot(sp); if (sp) v1[5] -= THRESH; } \
        { v1[6] += rcv[6]; bool sp = v1[6] >= THRESH; mk6 = __ballot(sp); if (sp) v1[6] -= THRESH; } \
        { v1[7] += rcv[7]; bool sp = v1[7] >= THRESH; mk7 = __ballot(sp); if (sp) v1[7] -= THRESH; } \
        if (L == 0) {                                                          \
            smask_lo[t * 8 + 0] = (int)(mk0 & 0xffffffffull); smask_hi[t * 8 + 0] = (int)(mk0 >> 32); \
            smask_lo[t * 8 + 1] = (int)(mk1 & 0xffffffffull); smask_hi[t * 8 + 1] = (int)(mk1 >> 32); \
            smask_lo[t * 8 + 2] = (int)(mk2 & 0xffffffffull); smask_hi[t * 8 + 2] = (int)(mk2 >> 32); \
            smask_lo[t * 8 + 3] = (int)(mk3 & 0xffffffffull); smask_hi[t * 8 + 3] = (int)(mk3 >> 32); \
            smask_lo[t * 8 + 4] = (int)(mk4 & 0xffffffffull); smask_hi[t * 8 + 4] = (int)(mk4 >> 32); \
            smask_lo[t * 8 + 5] = (int)(mk5 & 0xffffffffull); smask_hi[t * 8 + 5] = (int)(mk5 >> 32); \
            smask_lo[t * 8 + 6] = (int)(mk6 & 0xffffffffull); smask_hi[t * 8 + 6] = (int)(mk6 >> 32); \
            smask_lo[t * 8 + 7] = (int)(mk7 & 0xffffffffull); smask_hi[t * 8 + 7] = (int)(mk7 >> 32); \
        }                                                                      \
        int Sl = (int)__popcll(mk0 & below) + (int)__popcll(mk1 & below) +     \
                 (int)__popcll(mk2 & below) + (int)__popcll(mk3 & below) +     \
                 (int)__popcll(mk4 & below) + (int)__popcll(mk5 & below) +     \
                 (int)__popcll(mk6 & below) + (int)__popcll(mk7 & below);      \
        int run = 0;                                                           \
        if ((mk0 >> L) & 1ull) { slist[Sl + run] = 8 * L + 0; ++run; }         \
        if ((mk1 >> L) & 1ull) { slist[Sl + run] = 8 * L + 1; ++run; }         \
        if ((mk2 >> L) & 1ull) { slist[Sl + run] = 8 * L + 2; ++run; }         \
        if ((mk3 >> L) & 1ull) { slist[Sl + run] = 8 * L + 3; ++run; }         \
        if ((mk4 >> L) & 1ull) { slist[Sl + run] = 8 * L + 4; ++run; }         \
        if ((mk5 >> L) & 1ull) { slist[Sl + run] = 8 * L + 5; ++run; }         \
        if ((mk6 >> L) & 1ull) { slist[Sl + run] = 8 * L + 6; ++run; }         \
        if ((mk7 >> L) & 1ull) { slist[Sl + run] = 8 * L + 7; ++run; }         \
        pcnt = (int)__popcll(mk0) + (int)__popcll(mk1) + (int)__popcll(mk2) +  \
               (int)__popcll(mk3) + (int)__popcll(mk4) + (int)__popcll(mk5) +  \
               (int)__popcll(mk6) + (int)__popcll(mk7);                        \
    }

    // prologue: producers fill window 0
    if (wid != 0) FILL_HALF(0)
    __syncthreads();

    // main loop: 16 windows x 16 steps; producers stay one window ahead
    for (int h = 0; h < 16; ++h) {
        if (wid == 0) {
            const int sbase = (h & 1) * 16;
            for (int r = 0; r < 16; ++r) {
                SNN_STEP(h * 16 + r, sbase + r)
            }
        } else if (h + 1 < 16) {
            FILL_HALF(h + 1)
        }
        __syncthreads();
    }
#undef SNN_STEP
#undef FILL_HALF

    // ---- phase 2: output neurons, off the recurrence (all 192 threads) ----
    for (int j = tid; j < H_; j += 192) {
#pragma unroll
        for (int o = 0; o < O_; ++o) w2t[j * 12 + o] = w2[o * H_ + j];
    }
    __syncthreads();

    for (int tt = tid; tt < T_; tt += 192) {
        float s0 = 0.f, s1 = 0.f, s2 = 0.f, s3 = 0.f, s4 = 0.f, s5 = 0.f,
              s6 = 0.f, s7 = 0.f, s8 = 0.f, s9 = 0.f, s10 = 0.f;
#pragma unroll
        for (int r = 0; r < 8; ++r) {
            unsigned long long m =
                ((unsigned long long)(unsigned)smask_lo[tt * 8 + r]) |
                (((unsigned long long)(unsigned)smask_hi[tt * 8 + r]) << 32);
            while (m) {
                int l = __builtin_ctzll(m);
                m &= m - 1;
                const float* wp = &w2t[(8 * l + r) * 12];
                s0 += wp[0]; s1 += wp[1]; s2 += wp[2]; s3 += wp[3];
                s4 += wp[4]; s5 += wp[5]; s6 += wp[6]; s7 += wp[7];
                s8 += wp[8]; s9 += wp[9]; s10 += wp[10];
            }
        }
        float* ip = &i2s[tt * 12];
        ip[0] = s0; ip[1] = s1; ip[2] = s2; ip[3] = s3; ip[4] = s4;
        ip[5] = s5; ip[6] = s6; ip[7] = s7; ip[8] = s8; ip[9] = s9; ip[10] = s10;
    }
    __syncthreads();

    if (tid < O_) {
        float v2 = 0.f, osum = 0.f;
        for (int t = 0; t < T_; ++t) {
            v2 = v2 + i2s[t * 12 + tid] - OLEAK_;
            v2 = v2 > 0.f ? v2 : 0.f;
            osum += v2;
        }
        out[b * O_ + tid] = osum * (1.0f / (float)T_);
    }
}

// ---------------------------------------------------------------------------
extern "C" void kernel_launch(void* const* d_in, const int* in_sizes, int n_in,
                              void* d_out, int out_size, void* d_ws, size_t ws_size,
                              hipStream_t stream) {
    const float* x     = (const float*)d_in[0];   // (B,T,C)
    const float* w1    = (const float*)d_in[1];   // (H,C)
    const float* w_rec = (const float*)d_in[2];   // (H,H)
    const float* w2    = (const float*)d_in[3];   // (O,H)
    float* out = (float*)d_out;                   // (B,O)

    const size_t PART = (size_t)B_ * T_ * H_ * sizeof(float);   // 32 MB
    const size_t WRT  = (size_t)H_ * H_ * sizeof(float);        // 1 MB

    int S = 1;
    if (ws_size >= 4 * PART + WRT) S = 4;
    else if (ws_size >= 2 * PART + WRT) S = 2;

    float* P   = (float*)d_ws;
    float* wrT = (float*)((char*)d_ws + (size_t)S * PART);

    transpose_wrec<<<dim3(H_ / 32, H_ / 32), dim3(32, 8), 0, stream>>>(w_rec, wrT);

    switch (S) {
        case 4:
            gemm_ff<4><<<dim3(4, 128, 4), dim3(256), 0, stream>>>(x, w1, P);
            snn_rec<4><<<dim3(B_), dim3(192), 0, stream>>>(P, wrT, w2, out);
            break;
        case 2:
            gemm_ff<2><<<dim3(4, 128, 2), dim3(256), 0, stream>>>(x, w1, P);
            snn_rec<2><<<dim3(B_), dim3(192), 0, stream>>>(P, wrT, w2, out);
            break;
        default:
            gemm_ff<1><<<dim3(4, 128, 1), dim3(256), 0, stream>>>(x, w1, P);
            snn_rec<1><<<dim3(B_), dim3(192), 0, stream>>>(P, wrT, w2, out);
            break;
    }
}